// Round 9
// baseline (39797.308 us; speedup 1.0000x reference)
//
#include <hip/hip_runtime.h>
#include <math.h>

#define BB 32
#define TIN 256
#define TOUT 400
#define EE 512
#define AA 128
#define KSZ 31
#define PRE 256
#define DD 1024
#define NMEL 80
#define NF 32
#define KP 4360          // padded K-rows per LDS weight column (16B-aligned rows)
#define NRING 8          // state ring depth (see staleness analysis in gbar)

typedef _Float16 h2 __attribute__((ext_vector_type(2)));
typedef _Float16 h4 __attribute__((ext_vector_type(4)));
typedef _Float16 h8 __attribute__((ext_vector_type(8)));
typedef float f4 __attribute__((ext_vector_type(4)));

__device__ __forceinline__ float fast_sigmoid(float x) { return 1.f / (1.f + __expf(-x)); }
__device__ __forceinline__ float fast_tanh(float x) {
  float ax = fabsf(x);
  float e = __expf(fminf(2.f * ax, 40.f));
  return copysignf((e - 1.f) / (e + 1.f), x);
}
__device__ __forceinline__ float d2(h2 a, h2 b, float c) {
#if __has_builtin(__builtin_amdgcn_fdot2)
  return __builtin_amdgcn_fdot2(a, b, c, false);
#else
  return fmaf((float)a[0], (float)b[0], fmaf((float)a[1], (float)b[1], c));
#endif
}
__device__ __forceinline__ float dot8(h8 a, h8 b, float c) {
  c = d2((h2){a[0], a[1]}, (h2){b[0], b[1]}, c);
  c = d2((h2){a[2], a[3]}, (h2){b[2], b[3]}, c);
  c = d2((h2){a[4], a[5]}, (h2){b[4], b[5]}, c);
  c = d2((h2){a[6], a[7]}, (h2){b[6], b[7]}, c);
  return c;
}

// ---- access helpers ----
// Cached 16B load (L1/L2). State coherence: ring addressing + periodic
// agent-acquire fence (buffer_inv) every 4 steps — writers store system-scope
// (straight to LLC, L2 never dirty), so post-inv refills are always fresh.
__device__ __forceinline__ h8 ldg16_ro(const _Float16* p) {
  h8 r;
  asm volatile("global_load_dwordx4 %0, %1, off" : "=v"(r) : "v"(p));
  return r;
}
// system-scope (LLC) stores: bypass L2 -> never leave stale/dirty L2 lines
__device__ __forceinline__ void st_cc8(_Float16* p, h4 x) {
  union { unsigned long long u; h4 h; } c; c.h = x;
  __hip_atomic_store((unsigned long long*)p, c.u, __ATOMIC_RELAXED,
                     __HIP_MEMORY_SCOPE_SYSTEM);
}
__device__ __forceinline__ void st_cc4f(float* p, float x) {
  union { unsigned u; float f; } c; c.f = x;
  __hip_atomic_store((unsigned*)p, c.u, __ATOMIC_RELAXED,
                     __HIP_MEMORY_SCOPE_SYSTEM);
}

#define MFMA16(a, b, c) __builtin_amdgcn_mfma_f32_16x16x32_f16((a), (b), (c), 0, 0, 0)

// ---------------- setup kernels ----------------
__global__ void k_prenet(const float* __restrict__ targets,
                         const float* __restrict__ w1, const float* __restrict__ b1,
                         const float* __restrict__ w2, const float* __restrict__ b2,
                         _Float16* __restrict__ px) {
  int t = blockIdx.x >> 5, b = blockIdx.x & 31, j = threadIdx.x;
  __shared__ float din[NMEL];
  __shared__ float hl[PRE];
  if (j < NMEL) din[j] = (t == 0) ? 0.f : targets[(b * TOUT + (t - 1)) * NMEL + j];
  __syncthreads();
  float s = b1[j];
#pragma unroll
  for (int k = 0; k < NMEL; ++k) s = fmaf(din[k], w1[k * PRE + j], s);
  hl[j] = fmaxf(s, 0.f);
  __syncthreads();
  float s2 = b2[j];
  for (int k = 0; k < PRE; ++k) s2 = fmaf(hl[k], w2[k * PRE + j], s2);
  px[(size_t)t * 8192 + b * 256 + j] = (_Float16)fmaxf(s2, 0.f);
}

__global__ void k_keys(const float* __restrict__ memory, const float* __restrict__ mw,
                       const float* __restrict__ mb, _Float16* __restrict__ keys) {
  int row = blockIdx.x, a = threadIdx.x;
  __shared__ float mrow[EE];
  for (int i = a; i < EE; i += AA) mrow[i] = memory[row * EE + i];
  __syncthreads();
  float s = mb[a];
  for (int k = 0; k < EE; ++k) s = fmaf(mrow[k], mw[k * AA + a], s);
  keys[row * AA + a] = (_Float16)s;
}

__global__ void k_locM(const float* __restrict__ cw, const float* __restrict__ cb,
                       const float* __restrict__ ldw, const float* __restrict__ ldb,
                       float* __restrict__ M, float* __restrict__ Lb) {
  int a = threadIdx.x;
  for (int kk = 0; kk < KSZ; ++kk) {
    float s = 0.f;
    for (int f = 0; f < NF; ++f) s = fmaf(cw[kk * NF + f], ldw[f * AA + a], s);
    M[kk * AA + a] = s;
  }
  float s = ldb[a];
  for (int f = 0; f < NF; ++f) s = fmaf(cb[f], ldw[f * AA + a], s);
  Lb[a] = s;
}

// qw [1024][128] -> qwT [128][1024] fp16
__global__ void k_castT(const float* __restrict__ qw, _Float16* __restrict__ qwT) {
  int i = blockIdx.x * 256 + threadIdx.x;  // 131072
  int k = i >> 7, a = i & 127;
  qwT[a * 1024 + k] = (_Float16)qw[k * 128 + a];
}

// memory [b][t][e] -> memT [b][e][t] fp16, tiled transpose
__global__ void k_memT(const float* __restrict__ mem, _Float16* __restrict__ memT) {
  __shared__ _Float16 tile[32][33];
  int b = blockIdx.x >> 7;
  int tt = (blockIdx.x >> 4) & 7;
  int ee = blockIdx.x & 15;
  int r = threadIdx.x >> 5, cc = threadIdx.x & 31;
#pragma unroll
  for (int i = 0; i < 4; ++i) {
    int t = tt * 32 + r + i * 8, e = ee * 32 + cc;
    tile[r + i * 8][cc] = (_Float16)mem[((size_t)b * 256 + t) * 512 + e];
  }
  __syncthreads();
#pragma unroll
  for (int i = 0; i < 4; ++i) {
    int e = ee * 32 + r + i * 8, t = tt * 32 + cc;
    memT[((size_t)b * 512 + e) * 256 + t] = tile[cc][r + i * 8];
  }
}

// proj+gate weights transposed: pwpT[o][k], o<80 = mel col o, o=80 = gate
__global__ void k_permP(const float* __restrict__ pw, const float* __restrict__ gw,
                        _Float16* __restrict__ pwpT) {
  int i = blockIdx.x * 256 + threadIdx.x;  // 128*1536
  int o = i / 1536, k = i % 1536;
  float v = (o < 80) ? pw[k * 80 + o] : ((o == 80) ? gw[k] : 0.f);
  pwpT[i] = (_Float16)v;
}

// gate-interleave + per-block-slice permute: col p=4j+g; block B=j>>2 owns 16
// cols; c=4*(j&3)+g; dst[(B*16+c)*KP + row_off + k]
__global__ void k_perm(const float* __restrict__ src, _Float16* __restrict__ dst,
                       int rows, int row_off) {
  int idx = blockIdx.x * 256 + threadIdx.x;
  int k = idx >> 10, j = idx & 1023;
  if (k >= rows) return;
  const float* s = src + (size_t)k * 4096 + j;
  int base = (j >> 2) * 16 + 4 * (j & 3);
#pragma unroll
  for (int g = 0; g < 4; ++g)
    dst[(size_t)(base + g) * KP + row_off + k] = (_Float16)s[g * 1024];
}

// ---------------- persistent decoder ----------------
struct __align__(16) AttnS {
  _Float16 h1l[1024];
  _Float16 ctx16[EE];
  _Float16 wsm16[TIN];
  float wl[TIN + KSZ - 1];
  float qpart[512];
  float qp[AA];
  float red[TIN];
  float epart[512];
  float pred[512];
};

// Grid barrier (round-2-verified protocol) + optional agent acquire fence
// every 4 steps (ring staleness coverage — see round-8 analysis).
__device__ __forceinline__ void gbar(int* bar, int ord, int tid, bool inv) {
  __syncthreads();                       // drain vm+lds; order pre-barrier ops
  const int B = blockIdx.x;
  const int target = ord + 1;
  if (tid == 0)
    __hip_atomic_store(bar + B * 4, target, __ATOMIC_RELAXED,
                       __HIP_MEMORY_SCOPE_SYSTEM);
  if (B == 255) {                        // scanner block (idle during attn)
    int done;
    do {
      int v = target;
      if (tid < 256)
        v = __hip_atomic_load(bar + tid * 4, __ATOMIC_RELAXED,
                              __HIP_MEMORY_SCOPE_SYSTEM);
      done = __syncthreads_and(v >= target);
    } while (!done);
    if (tid < 8)
      __hip_atomic_store(bar + 1024 + tid * 16, target, __ATOMIC_RELAXED,
                         __HIP_MEMORY_SCOPE_SYSTEM);
  } else if (tid == 0) {
    while (__hip_atomic_load(bar + 1024 + (B & 7) * 16, __ATOMIC_RELAXED,
                             __HIP_MEMORY_SCOPE_SYSTEM) < target) { /* spin */ }
  }
  if (inv && tid == 0)
    __builtin_amdgcn_fence(__ATOMIC_ACQUIRE, "agent");  // buffer_inv: L1+L2
  __syncthreads();                       // realign + order loads after inv
}

// LSTM phase via MFMA (identical to round 8 — loop must stay byte-identical
// for the stopwatch subtraction to be clean).
template <int LRO, int LA, int LB, int LC, int WOFF>
__device__ __forceinline__ void lstm_phase(
    const _Float16* __restrict__ Wl, float* __restrict__ zsP,
    _Float16* __restrict__ hbuf, float* __restrict__ cstL,
    const float* __restrict__ gbl,
    const _Float16* __restrict__ ro, const _Float16* __restrict__ ca,
    const _Float16* __restrict__ cb2, const _Float16* __restrict__ cc3,
    _Float16* __restrict__ hout, int B, int tid) {
  const int w = tid >> 6, l = tid & 63;
  const int lr = l & 15, lk = l >> 4;
  const int kb = w * 32 + lk * 8;          // wave's K offset within each 256-chunk
  constexpr int NRO = LRO / 256, NA = LA / 256, NB = LB / 256, NC = LC / 256;
  constexpr int NT = NRO + NA + NB + NC;

  // (1) x fragments: issue everything, no waits in between
  h8 xa[2 * NT];
  if (NRO > 0) {
#pragma unroll
    for (int i = 0; i < NRO; ++i) {
      const _Float16* xp = ro + kb + i * 256;
      xa[2 * i]     = ldg16_ro(xp + lr * LRO);
      xa[2 * i + 1] = ldg16_ro(xp + (16 + lr) * LRO);
    }
  }
  if (NA > 0) {
#pragma unroll
    for (int i = 0; i < NA; ++i) {
      const _Float16* xp = ca + kb + i * 256;
      xa[2 * (NRO + i)]     = ldg16_ro(xp + lr * LA);
      xa[2 * (NRO + i) + 1] = ldg16_ro(xp + (16 + lr) * LA);
    }
  }
  if (NB > 0) {
#pragma unroll
    for (int i = 0; i < NB; ++i) {
      const _Float16* xp = cb2 + kb + i * 256;
      xa[2 * (NRO + NA + i)]     = ldg16_ro(xp + lr * LB);
      xa[2 * (NRO + NA + i) + 1] = ldg16_ro(xp + (16 + lr) * LB);
    }
  }
  if (NC > 0) {
#pragma unroll
    for (int i = 0; i < NC; ++i) {
      const _Float16* xp = cc3 + kb + i * 256;
      xa[2 * (NRO + NA + NB + i)]     = ldg16_ro(xp + lr * LC);
      xa[2 * (NRO + NA + NB + i) + 1] = ldg16_ro(xp + (16 + lr) * LC);
    }
  }

  // (2) weight fragments from LDS (overlap with in-flight global loads)
  const _Float16* wr = Wl + lr * KP + WOFF + kb;
  h8 bf[NT];
#pragma unroll
  for (int j = 0; j < NT; ++j) bf[j] = *(const h8*)(wr + j * 256);

  // (3) single drain; fence the scheduler so MFMAs can't hoist above it
  asm volatile("s_waitcnt vmcnt(0)");
  __builtin_amdgcn_sched_barrier(0);

  // (4) MFMA burst
  f4 acc0 = {0.f, 0.f, 0.f, 0.f};
  f4 acc1 = {0.f, 0.f, 0.f, 0.f};
#pragma unroll
  for (int j = 0; j < NT; ++j) {
    acc0 = MFMA16(xa[2 * j], bf[j], acc0);
    acc1 = MFMA16(xa[2 * j + 1], bf[j], acc1);
  }

  // D layout (m89): col = lane&15, row = (lane>>4)*4 + reg.
#pragma unroll
  for (int r = 0; r < 4; ++r) {
    zsP[w * 544 + lr * 34 + lk * 4 + r] = acc0[r];
    zsP[w * 544 + lr * 34 + 16 + lk * 4 + r] = acc1[r];
  }
  __syncthreads();
  if (tid < 128) {
    int jj = tid >> 5, bb = tid & 31;
    float z0 = gbl[4 * jj + 0], z1 = gbl[4 * jj + 1];
    float z2 = gbl[4 * jj + 2], z3 = gbl[4 * jj + 3];
#pragma unroll
    for (int ww = 0; ww < 8; ++ww) {
      const float* p = zsP + ww * 544 + bb;
      z0 += p[(4 * jj + 0) * 34];
      z1 += p[(4 * jj + 1) * 34];
      z2 += p[(4 * jj + 2) * 34];
      z3 += p[(4 * jj + 3) * 34];
    }
    float ig = fast_sigmoid(z0), fg = fast_sigmoid(z1);
    float gg = fast_tanh(z2), og = fast_sigmoid(z3);
    float cn = fg * cstL[jj * 32 + bb] + ig * gg;
    cstL[jj * 32 + bb] = cn;
    hbuf[bb * 4 + jj] = (_Float16)(og * fast_tanh(cn));
  }
  __syncthreads();
  if (tid < 32)
    st_cc8(hout + tid * 1024 + B * 4, *(const h4*)(hbuf + tid * 4));
}

__device__ __forceinline__ void attn_phase(
    AttnS* A, const _Float16* __restrict__ memT, const _Float16* __restrict__ keys16,
    const _Float16* __restrict__ h1,
    const _Float16* __restrict__ qwT, const float* __restrict__ qb,
    const float* __restrict__ vw, const float* __restrict__ vb,
    const float* __restrict__ Mf, const float* __restrict__ Lbf,
    const _Float16* __restrict__ pwpT, const float* __restrict__ pb,
    const float* __restrict__ gb_out,
    float* __restrict__ wcumL, _Float16* __restrict__ ctxo,
    float* __restrict__ out, int b, int step, int tid) {
  if (tid < 256) ((h4*)A->h1l)[tid] = *(const h4*)(h1 + b * 1024 + tid * 4);
  if (tid < TIN + KSZ - 1) {
    int tt = tid - 15;
    A->wl[tid] = (tt >= 0 && tt < TIN) ? wcumL[tt] : 0.f;
  }
  __syncthreads();
  {  // qp partials
    int a = tid & 127, kq = tid >> 7;
    const _Float16* hr = A->h1l + kq * 256;
    const _Float16* qr = qwT + a * 1024 + kq * 256;
    float s = 0.f;
#pragma unroll 4
    for (int i = 0; i < 32; ++i)
      s = dot8(*(const h8*)(hr + i * 8), *(const h8*)(qr + i * 8), s);
    A->qpart[kq * AA + a] = s;
  }
  __syncthreads();
  if (tid < AA)
    A->qp[tid] = A->qpart[tid] + A->qpart[AA + tid] + A->qpart[2 * AA + tid] +
                 A->qpart[3 * AA + tid] + qb[tid];
  __syncthreads();
  {  // energies
    int t = tid & 255, ah = tid >> 8;
    const _Float16* keyrow = keys16 + ((size_t)(b * TIN + t)) * AA + ah * 64;
    h8 kv[8];
#pragma unroll
    for (int i = 0; i < 8; ++i) kv[i] = *(const h8*)(keyrow + i * 8);
    float e = (ah == 0) ? vb[0] : 0.f;
#pragma unroll
    for (int half = 0; half < 2; ++half) {
      int c2 = ah * 64 + half * 32;
      float l32[32];
      const float4* Lb4 = (const float4*)(Lbf + c2);
#pragma unroll
      for (int q = 0; q < 8; ++q) {
        float4 v = Lb4[q];
        l32[4 * q] = v.x; l32[4 * q + 1] = v.y; l32[4 * q + 2] = v.z; l32[4 * q + 3] = v.w;
      }
      for (int kk = 0; kk < KSZ; ++kk) {
        float wk = A->wl[t + kk];
        const float4* Mr = (const float4*)(Mf + kk * AA + c2);
#pragma unroll
        for (int q = 0; q < 8; ++q) {
          float4 m = Mr[q];
          l32[4 * q]     = fmaf(wk, m.x, l32[4 * q]);
          l32[4 * q + 1] = fmaf(wk, m.y, l32[4 * q + 1]);
          l32[4 * q + 2] = fmaf(wk, m.z, l32[4 * q + 2]);
          l32[4 * q + 3] = fmaf(wk, m.w, l32[4 * q + 3]);
        }
      }
#pragma unroll
      for (int aa = 0; aa < 32; ++aa) {
        float kf = (float)kv[(half * 32 + aa) >> 3][(half * 32 + aa) & 7];
        float u = fast_tanh(A->qp[c2 + aa] + kf + l32[aa]);
        e = fmaf(u, vw[c2 + aa], e);
      }
    }
    A->epart[ah * TIN + t] = e;
  }
  __syncthreads();
  float e = 0.f;
  if (tid < TIN) { e = A->epart[tid] + A->epart[TIN + tid]; A->red[tid] = e; }
  __syncthreads();
  for (int s = 128; s > 0; s >>= 1) {
    if (tid < s) A->red[tid] = fmaxf(A->red[tid], A->red[tid + s]);
    __syncthreads();
  }
  float mx = A->red[0];
  __syncthreads();
  float pp = 0.f;
  if (tid < TIN) { pp = __expf(e - mx); A->red[tid] = pp; }
  __syncthreads();
  for (int s = 128; s > 0; s >>= 1) {
    if (tid < s) A->red[tid] += A->red[tid + s];
    __syncthreads();
  }
  if (tid < TIN) {
    float w = pp / A->red[0];
    A->wsm16[tid] = (_Float16)w;
    wcumL[tid] += w;
    st_cc4f(out + 1036800 + (size_t)b * TOUT * TIN + step * TIN + tid, w);
  }
  __syncthreads();
  {  // ctx = w @ memory via memT rows (cached, read-only)
    const _Float16* mr = memT + ((size_t)(b * EE + tid)) * TIN;
    float s = 0.f;
#pragma unroll 4
    for (int i = 0; i < 32; ++i)
      s = dot8(*(const h8*)(A->wsm16 + i * 8), *(const h8*)(mr + i * 8), s);
    A->ctx16[tid] = (_Float16)s;
  }
  __syncthreads();
  if (tid < 128)
    st_cc8(ctxo + b * 512 + tid * 4, *(const h4*)(A->ctx16 + tid * 4));
  {  // mel(80)+gate(1)
    int kq = tid >> 7, oo = tid & 127;
    if (oo < 81) {
      const _Float16* pr = pwpT + oo * 1536 + kq * 384;
      float s = 0.f;
#pragma unroll 2
      for (int kk = 0; kk < 384; kk += 8) {
        int k = kq * 384 + kk;
        h8 xv = (k < DD) ? *(const h8*)(A->h1l + k) : *(const h8*)(A->ctx16 + (k - DD));
        s = dot8(xv, *(const h8*)(pr + kk), s);
      }
      A->pred[tid] = s;
    }
  }
  __syncthreads();
  if (tid < 81) {
    float s = A->pred[tid] + A->pred[128 + tid] + A->pred[256 + tid] + A->pred[384 + tid];
    if (tid < 80)
      st_cc4f(out + (size_t)b * TOUT * NMEL + step * NMEL + tid, s + pb[tid]);
    else
      st_cc4f(out + 1024000 + b * TOUT + step, s + gb_out[0]);
  }
}

__global__ __launch_bounds__(512, 2) void k_decoder(
    const _Float16* __restrict__ memT, const _Float16* __restrict__ px,
    const _Float16* __restrict__ keys16, const _Float16* __restrict__ Wstage,
    const float* __restrict__ l0b, const float* __restrict__ l1b,
    const _Float16* __restrict__ qwT, const float* __restrict__ qb,
    const float* __restrict__ vw, const float* __restrict__ vb,
    const float* __restrict__ Mf, const float* __restrict__ Lbf,
    const _Float16* __restrict__ pwpT, const float* __restrict__ pb,
    const float* __restrict__ gb_out,
    char* state, float* out) {
  extern __shared__ char smem[];
  _Float16* Wl   = (_Float16*)smem;                // 139,520
  char* uni      = smem + 139520;                  // 17,664 union
  float* zsP     = (float*)uni;                    // 17,408 (lstm mfma partials)
  _Float16* hbuf = (_Float16*)(uni + 17408);       // 256   (lstm)
  AttnS* A       = (AttnS*)uni;                    // 12,408 (attn)
  float* cst     = (float*)(smem + 157184);        // 1,024
  float* gb      = (float*)(smem + 158208);        // 128
  float* wcumL   = (float*)(smem + 158336);        // 1,024  -> total 159,360

  // state rings: 8 x h0(64KB) | 8 x h1(64KB) | 8 x ctx(32KB) | barrier flags
  _Float16* h0R  = (_Float16*)state;               // slot*32768 elems
  _Float16* h1R  = (_Float16*)(state + 524288);
  _Float16* ctxR = (_Float16*)(state + 1048576);   // slot*16384 elems
  int* bar = (int*)(state + 1310720);  // arrive[256]@16B + release flags

  const int B = blockIdx.x, tid = threadIdx.x;

  // write back any dirty pre-decoder lines before the first buffer_inv
  __builtin_amdgcn_fence(__ATOMIC_RELEASE, "agent");

  {  // load this block's weight slice into LDS (read-only, once)
    const float4* src = (const float4*)(Wstage + (size_t)B * 16 * KP);
    float4* dst = (float4*)Wl;
    for (int i = tid; i < 16 * KP * 2 / 16; i += 512) dst[i] = src[i];
  }
  if (tid < 256) { cst[tid] = 0.f; wcumL[tid] = 0.f; }
  if (tid < 32) {
    int c = tid & 15;
    const float* bb = (tid < 16) ? l0b : l1b;
    gb[tid] = bb[(c & 3) * 1024 + B * 4 + (c >> 2)];
  }
  __syncthreads();

  for (int t = 0; t < TOUT; ++t) {
    const int s = t & (NRING - 1), sm1 = (t + NRING - 1) & (NRING - 1);
    _Float16* h0n = h0R + s * 32768;     // h0 new (written in LSTM0)
    _Float16* h0o = h0R + sm1 * 32768;   // h0 old
    _Float16* h1n = h1R + s * 32768;
    _Float16* h1o = h1R + sm1 * 32768;
    _Float16* ctn = ctxR + s * 16384;    // ctx written by attn this step
    _Float16* cto = ctxR + sm1 * 16384;  // ctx from previous step
    const bool inv = ((t & 3) == 3);     // 2 inv phases per ring cycle

    // LSTM0: x = [px_t(256) | ctx_old(512) | h0_old(1024)]  (cached loads)
    lstm_phase<256, 512, 1024, 0, 0>(Wl, zsP, hbuf, cst, gb,
                                     px + (size_t)t * 8192, cto, h0o,
                                     px, h0n, B, tid);
    gbar(bar, 3 * t + 0, tid, false);
    // LSTM1: x = [h0_new(1024) | ctx_old(512) | h1_old(1024)]
    lstm_phase<0, 1024, 512, 1024, 1792>(Wl, zsP, hbuf, cst + 128, gb + 16,
                                         px, h0n, cto, h1o,
                                         h1n, B, tid);
    gbar(bar, 3 * t + 1, tid, false);
    if (B < BB)
      attn_phase(A, memT, keys16, h1n, qwT, qb, vw, vb, Mf, Lbf,
                 pwpT, pb, gb_out, wcumL, ctn, out, B, t, tid);
    gbar(bar, 3 * t + 2, tid, inv);
  }

  // ---- ROUND-9 STOPWATCH TAIL (loop above is byte-identical to round 8) ----
  // 262,144 x 16 = 4,194,304 dependent FMAs per thread ~= 16.8M shader cycles
  // (dep latency ~4cy, 2 waves/SIMD saturate issue -> wall = 16.8Mcy / f).
  // dur - 30.2ms reads the effective clock: 2.4GHz -> +7.0ms; 1.2GHz -> +14ms;
  // 600MHz -> +28ms. This decides structural-ghost vs low-clock (see journal).
  {
    float x = (float)tid * 1e-7f + 1.1f;
    const float y = 1.0000001f, c = 0.0625f;
    for (int i = 0; i < 262144; ++i) {
#pragma unroll
      for (int u = 0; u < 16; ++u) x = fmaf(x, y, c);
      asm volatile("" : "+v"(x));     // pin the dependency chain each iter
    }
    asm volatile("" :: "v"(x));       // keep live, no DCE
  }
}

// ---------------- host ----------------
extern "C" void kernel_launch(void* const* d_in, const int* in_sizes, int n_in,
                              void* d_out, int out_size, void* d_ws, size_t ws_size,
                              hipStream_t stream) {
  const float* memory  = (const float*)d_in[0];
  const float* targets = (const float*)d_in[1];
  const float* p1w = (const float*)d_in[3];
  const float* p1b = (const float*)d_in[4];
  const float* p2w = (const float*)d_in[5];
  const float* p2b = (const float*)d_in[6];
  const float* l0k = (const float*)d_in[7];
  const float* l0r = (const float*)d_in[8];
  const float* l0b = (const float*)d_in[9];
  const float* l1k = (const float*)d_in[10];
  const float* l1r = (const float*)d_in[11];
  const float* l1b = (const float*)d_in[12];
  const float* qw  = (const float*)d_in[13];
  const float* qb  = (const float*)d_in[14];
  const float* mw  = (const float*)d_in[15];
  const float* mb  = (const float*)d_in[16];
  const float* vw  = (const float*)d_in[17];
  const float* vb  = (const float*)d_in[18];
  const float* cw  = (const float*)d_in[19];
  const float* cb  = (const float*)d_in[20];
  const float* ldw = (const float*)d_in[21];
  const float* ldb = (const float*)d_in[22];
  const float* pw  = (const float*)d_in[23];
  const float* pb  = (const float*)d_in[24];
  const float* gw  = (const float*)d_in[25];
  const float* gb  = (const float*)d_in[26];

  char* W = (char*)d_ws;
  _Float16* px16   = (_Float16*)(W + 0);           //  6,553,600
  _Float16* keys16 = (_Float16*)(W + 6553600);     //  2,097,152
  _Float16* memT16 = (_Float16*)(W + 8650752);     //  8,388,608
  _Float16* qwT16  = (_Float16*)(W + 17039360);    //    262,144
  _Float16* pwpT   = (_Float16*)(W + 17301504);    //    393,216
  float*    Mf     = (float*)   (W + 17694720);    //     15,872
  float*    Lbf    = (float*)   (W + 17710592);    //        512
  _Float16* Wstage = (_Float16*)(W + 17711104);    // 35,717,120
  char*     state  =             W + 53428224;     //  1,318,912 (rings + bar)
  float* out = (float*)d_out;

  // zero state rings + barrier flags (ws re-poisoned before every call)
  hipMemsetAsync(state, 0, 1318912, stream);

  k_prenet<<<TOUT * BB, PRE, 0, stream>>>(targets, p1w, p1b, p2w, p2b, px16);
  k_keys<<<BB * TIN, AA, 0, stream>>>(memory, mw, mb, keys16);
  k_locM<<<1, AA, 0, stream>>>(cw, cb, ldw, ldb, Mf, Lbf);
  k_memT<<<4096, 256, 0, stream>>>(memory, memT16);
  k_castT<<<(131072 + 255) / 256, 256, 0, stream>>>(qw, qwT16);
  k_permP<<<768, 256, 0, stream>>>(pw, gw, pwpT);
  // weight slices: rows [l0k 0..767 | l0r 768..1791 | l1k 1792..3327 | l1r 3328..4351]
  k_perm<<<(768 * 1024 + 255) / 256, 256, 0, stream>>>(l0k, Wstage, 768, 0);
  k_perm<<<(1024 * 1024 + 255) / 256, 256, 0, stream>>>(l0r, Wstage, 1024, 768);
  k_perm<<<(1536 * 1024 + 255) / 256, 256, 0, stream>>>(l1k, Wstage, 1536, 1792);
  k_perm<<<(1024 * 1024 + 255) / 256, 256, 0, stream>>>(l1r, Wstage, 1024, 1792 + 1536);

  void* args[] = {(void*)&memT16, (void*)&px16, (void*)&keys16, (void*)&Wstage,
                  (void*)&l0b, (void*)&l1b, (void*)&qwT16, (void*)&qb,
                  (void*)&vw, (void*)&vb, (void*)&Mf, (void*)&Lbf,
                  (void*)&pwpT, (void*)&pb, (void*)&gb,
                  (void*)&state, (void*)&out};
  hipLaunchCooperativeKernel((const void*)k_decoder, dim3(256), dim3(512), args,
                             159360, stream);
}

// Round 10
// 13636.230 us; speedup vs baseline: 2.9185x; 2.9185x over previous
//
#include <hip/hip_runtime.h>
#include <math.h>

#define BB 32
#define TIN 256
#define TOUT 400
#define EE 512
#define AA 128
#define KSZ 31
#define PRE 256
#define DD 1024
#define NMEL 80
#define NF 32
#define KP 4360          // padded K-rows per LDS weight column (16B-aligned rows)
#define NRING 8          // state ring depth (staleness analysis at gbar)

typedef _Float16 h2 __attribute__((ext_vector_type(2)));
typedef _Float16 h4 __attribute__((ext_vector_type(4)));
typedef _Float16 h8 __attribute__((ext_vector_type(8)));
typedef float f4 __attribute__((ext_vector_type(4)));

__device__ __forceinline__ float fast_sigmoid(float x) { return 1.f / (1.f + __expf(-x)); }
__device__ __forceinline__ float fast_tanh(float x) {
  float ax = fabsf(x);
  float e = __expf(fminf(2.f * ax, 40.f));
  return copysignf((e - 1.f) / (e + 1.f), x);
}
__device__ __forceinline__ float d2(h2 a, h2 b, float c) {
#if __has_builtin(__builtin_amdgcn_fdot2)
  return __builtin_amdgcn_fdot2(a, b, c, false);
#else
  return fmaf((float)a[0], (float)b[0], fmaf((float)a[1], (float)b[1], c));
#endif
}
__device__ __forceinline__ float dot8(h8 a, h8 b, float c) {
  c = d2((h2){a[0], a[1]}, (h2){b[0], b[1]}, c);
  c = d2((h2){a[2], a[3]}, (h2){b[2], b[3]}, c);
  c = d2((h2){a[4], a[5]}, (h2){b[4], b[5]}, c);
  c = d2((h2){a[6], a[7]}, (h2){b[6], b[7]}, c);
  return c;
}

// ---- access helpers ----
// Cached 16B load (L1/L2). Ring addressing + inv every 4 steps keeps cached
// state reads fresh (round-8-verified). Writers store system-scope (LLC).
__device__ __forceinline__ h8 ldg16_ro(const _Float16* p) {
  h8 r;
  asm volatile("global_load_dwordx4 %0, %1, off" : "=v"(r) : "v"(p));
  return r;
}
__device__ __forceinline__ void st_cc8(_Float16* p, h4 x) {
  union { unsigned long long u; h4 h; } c; c.h = x;
  __hip_atomic_store((unsigned long long*)p, c.u, __ATOMIC_RELAXED,
                     __HIP_MEMORY_SCOPE_SYSTEM);
}
__device__ __forceinline__ void st_cc4f(float* p, float x) {
  union { unsigned u; float f; } c; c.f = x;
  __hip_atomic_store((unsigned*)p, c.u, __ATOMIC_RELAXED,
                     __HIP_MEMORY_SCOPE_SYSTEM);
}
__device__ __forceinline__ float ld_cc4f(const float* p) {
  unsigned u = __hip_atomic_load((const unsigned*)p, __ATOMIC_RELAXED,
                                 __HIP_MEMORY_SCOPE_SYSTEM);
  union { unsigned u; float f; } c; c.u = u; return c.f;
}

#define MFMA16(a, b, c) __builtin_amdgcn_mfma_f32_16x16x32_f16((a), (b), (c), 0, 0, 0)

// ---------------- setup kernels ----------------
__global__ void k_prenet(const float* __restrict__ targets,
                         const float* __restrict__ w1, const float* __restrict__ b1,
                         const float* __restrict__ w2, const float* __restrict__ b2,
                         _Float16* __restrict__ px) {
  int t = blockIdx.x >> 5, b = blockIdx.x & 31, j = threadIdx.x;
  __shared__ float din[NMEL];
  __shared__ float hl[PRE];
  if (j < NMEL) din[j] = (t == 0) ? 0.f : targets[(b * TOUT + (t - 1)) * NMEL + j];
  __syncthreads();
  float s = b1[j];
#pragma unroll
  for (int k = 0; k < NMEL; ++k) s = fmaf(din[k], w1[k * PRE + j], s);
  hl[j] = fmaxf(s, 0.f);
  __syncthreads();
  float s2 = b2[j];
  for (int k = 0; k < PRE; ++k) s2 = fmaf(hl[k], w2[k * PRE + j], s2);
  px[(size_t)t * 8192 + b * 256 + j] = (_Float16)fmaxf(s2, 0.f);
}

__global__ void k_keys(const float* __restrict__ memory, const float* __restrict__ mw,
                       const float* __restrict__ mb, _Float16* __restrict__ keys) {
  int row = blockIdx.x, a = threadIdx.x;
  __shared__ float mrow[EE];
  for (int i = a; i < EE; i += AA) mrow[i] = memory[row * EE + i];
  __syncthreads();
  float s = mb[a];
  for (int k = 0; k < EE; ++k) s = fmaf(mrow[k], mw[k * AA + a], s);
  keys[row * AA + a] = (_Float16)s;
}

__global__ void k_locM(const float* __restrict__ cw, const float* __restrict__ cb,
                       const float* __restrict__ ldw, const float* __restrict__ ldb,
                       float* __restrict__ M, float* __restrict__ Lb) {
  int a = threadIdx.x;
  for (int kk = 0; kk < KSZ; ++kk) {
    float s = 0.f;
    for (int f = 0; f < NF; ++f) s = fmaf(cw[kk * NF + f], ldw[f * AA + a], s);
    M[kk * AA + a] = s;
  }
  float s = ldb[a];
  for (int f = 0; f < NF; ++f) s = fmaf(cb[f], ldw[f * AA + a], s);
  Lb[a] = s;
}

// qw [1024][128] -> qwT [128][1024] fp16
__global__ void k_castT(const float* __restrict__ qw, _Float16* __restrict__ qwT) {
  int i = blockIdx.x * 256 + threadIdx.x;  // 131072
  int k = i >> 7, a = i & 127;
  qwT[a * 1024 + k] = (_Float16)qw[k * 128 + a];
}

// memory [b][t][e] -> memT [b][e][t] fp16, tiled transpose
__global__ void k_memT(const float* __restrict__ mem, _Float16* __restrict__ memT) {
  __shared__ _Float16 tile[32][33];
  int b = blockIdx.x >> 7;
  int tt = (blockIdx.x >> 4) & 7;
  int ee = blockIdx.x & 15;
  int r = threadIdx.x >> 5, cc = threadIdx.x & 31;
#pragma unroll
  for (int i = 0; i < 4; ++i) {
    int t = tt * 32 + r + i * 8, e = ee * 32 + cc;
    tile[r + i * 8][cc] = (_Float16)mem[((size_t)b * 256 + t) * 512 + e];
  }
  __syncthreads();
#pragma unroll
  for (int i = 0; i < 4; ++i) {
    int e = ee * 32 + r + i * 8, t = tt * 32 + cc;
    memT[((size_t)b * 512 + e) * 256 + t] = tile[cc][r + i * 8];
  }
}

// proj+gate weights transposed: pwpT[o][k], o<80 = mel col o, o=80 = gate
__global__ void k_permP(const float* __restrict__ pw, const float* __restrict__ gw,
                        _Float16* __restrict__ pwpT) {
  int i = blockIdx.x * 256 + threadIdx.x;  // 128*1536
  int o = i / 1536, k = i % 1536;
  float v = (o < 80) ? pw[k * 80 + o] : ((o == 80) ? gw[k] : 0.f);
  pwpT[i] = (_Float16)v;
}

// gate-interleave + per-block-slice permute: col p=4j+g; block B=j>>2 owns 16
// cols; c=4*(j&3)+g; dst[(B*16+c)*KP + row_off + k]
__global__ void k_perm(const float* __restrict__ src, _Float16* __restrict__ dst,
                       int rows, int row_off) {
  int idx = blockIdx.x * 256 + threadIdx.x;
  int k = idx >> 10, j = idx & 1023;
  if (k >= rows) return;
  const float* s = src + (size_t)k * 4096 + j;
  int base = (j >> 2) * 16 + 4 * (j & 3);
#pragma unroll
  for (int g = 0; g < 4; ++g)
    dst[(size_t)(base + g) * KP + row_off + k] = (_Float16)s[g * 1024];
}

// ---------------- persistent decoder ----------------
struct __align__(16) AttnS {
  _Float16 h1l[1024];
  _Float16 ctx16[EE];
  _Float16 wsm16[TIN];
  float wl[TIN + KSZ - 1];
  float qpart[512];
  float qp[AA];
  float red[TIN];
  float epart[512];
  float pred[512];
};

// Grid barrier (round-2-verified protocol) + optional agent acquire fence
// every 4 steps (ring staleness coverage — round-8 analysis, passed).
__device__ __forceinline__ void gbar(int* bar, int ord, int tid, bool inv) {
  __syncthreads();                       // drain vm+lds; order pre-barrier ops
  const int B = blockIdx.x;
  const int target = ord + 1;
  if (tid == 0)
    __hip_atomic_store(bar + B * 4, target, __ATOMIC_RELAXED,
                       __HIP_MEMORY_SCOPE_SYSTEM);
  if (B == 255) {                        // scanner block
    int done;
    do {
      int v = target;
      if (tid < 256)
        v = __hip_atomic_load(bar + tid * 4, __ATOMIC_RELAXED,
                              __HIP_MEMORY_SCOPE_SYSTEM);
      done = __syncthreads_and(v >= target);
    } while (!done);
    if (tid < 8)
      __hip_atomic_store(bar + 1024 + tid * 16, target, __ATOMIC_RELAXED,
                         __HIP_MEMORY_SCOPE_SYSTEM);
  } else if (tid == 0) {
    while (__hip_atomic_load(bar + 1024 + (B & 7) * 16, __ATOMIC_RELAXED,
                             __HIP_MEMORY_SCOPE_SYSTEM) < target) { /* spin */ }
  }
  if (inv && tid == 0)
    __builtin_amdgcn_fence(__ATOMIC_ACQUIRE, "agent");  // buffer_inv: L1+L2
  __syncthreads();                       // realign + order loads after inv
}

// LSTM phase via MFMA (round-8-verified; unchanged)
template <int LRO, int LA, int LB, int LC, int WOFF>
__device__ __forceinline__ void lstm_phase(
    const _Float16* __restrict__ Wl, float* __restrict__ zsP,
    _Float16* __restrict__ hbuf, float* __restrict__ cstL,
    const float* __restrict__ gbl,
    const _Float16* __restrict__ ro, const _Float16* __restrict__ ca,
    const _Float16* __restrict__ cb2, const _Float16* __restrict__ cc3,
    _Float16* __restrict__ hout, int B, int tid) {
  const int w = tid >> 6, l = tid & 63;
  const int lr = l & 15, lk = l >> 4;
  const int kb = w * 32 + lk * 8;
  constexpr int NRO = LRO / 256, NA = LA / 256, NB = LB / 256, NC = LC / 256;
  constexpr int NT = NRO + NA + NB + NC;

  h8 xa[2 * NT];
  if (NRO > 0) {
#pragma unroll
    for (int i = 0; i < NRO; ++i) {
      const _Float16* xp = ro + kb + i * 256;
      xa[2 * i]     = ldg16_ro(xp + lr * LRO);
      xa[2 * i + 1] = ldg16_ro(xp + (16 + lr) * LRO);
    }
  }
  if (NA > 0) {
#pragma unroll
    for (int i = 0; i < NA; ++i) {
      const _Float16* xp = ca + kb + i * 256;
      xa[2 * (NRO + i)]     = ldg16_ro(xp + lr * LA);
      xa[2 * (NRO + i) + 1] = ldg16_ro(xp + (16 + lr) * LA);
    }
  }
  if (NB > 0) {
#pragma unroll
    for (int i = 0; i < NB; ++i) {
      const _Float16* xp = cb2 + kb + i * 256;
      xa[2 * (NRO + NA + i)]     = ldg16_ro(xp + lr * LB);
      xa[2 * (NRO + NA + i) + 1] = ldg16_ro(xp + (16 + lr) * LB);
    }
  }
  if (NC > 0) {
#pragma unroll
    for (int i = 0; i < NC; ++i) {
      const _Float16* xp = cc3 + kb + i * 256;
      xa[2 * (NRO + NA + NB + i)]     = ldg16_ro(xp + lr * LC);
      xa[2 * (NRO + NA + NB + i) + 1] = ldg16_ro(xp + (16 + lr) * LC);
    }
  }

  const _Float16* wr = Wl + lr * KP + WOFF + kb;
  h8 bf[NT];
#pragma unroll
  for (int j = 0; j < NT; ++j) bf[j] = *(const h8*)(wr + j * 256);

  asm volatile("s_waitcnt vmcnt(0)");
  __builtin_amdgcn_sched_barrier(0);

  f4 acc0 = {0.f, 0.f, 0.f, 0.f};
  f4 acc1 = {0.f, 0.f, 0.f, 0.f};
#pragma unroll
  for (int j = 0; j < NT; ++j) {
    acc0 = MFMA16(xa[2 * j], bf[j], acc0);
    acc1 = MFMA16(xa[2 * j + 1], bf[j], acc1);
  }

#pragma unroll
  for (int r = 0; r < 4; ++r) {
    zsP[w * 544 + lr * 34 + lk * 4 + r] = acc0[r];
    zsP[w * 544 + lr * 34 + 16 + lk * 4 + r] = acc1[r];
  }
  __syncthreads();
  if (tid < 128) {
    int jj = tid >> 5, bb = tid & 31;
    float z0 = gbl[4 * jj + 0], z1 = gbl[4 * jj + 1];
    float z2 = gbl[4 * jj + 2], z3 = gbl[4 * jj + 3];
#pragma unroll
    for (int ww = 0; ww < 8; ++ww) {
      const float* p = zsP + ww * 544 + bb;
      z0 += p[(4 * jj + 0) * 34];
      z1 += p[(4 * jj + 1) * 34];
      z2 += p[(4 * jj + 2) * 34];
      z3 += p[(4 * jj + 3) * 34];
    }
    float ig = fast_sigmoid(z0), fg = fast_sigmoid(z1);
    float gg = fast_tanh(z2), og = fast_sigmoid(z3);
    float cn = fg * cstL[jj * 32 + bb] + ig * gg;
    cstL[jj * 32 + bb] = cn;
    hbuf[bb * 4 + jj] = (_Float16)(og * fast_tanh(cn));
  }
  __syncthreads();
  if (tid < 32)
    st_cc8(hout + tid * 1024 + B * 4, *(const h4*)(hbuf + tid * 4));
}

// P2: energies for batch b, t-slice [sub*32, sub*32+32). 512 threads =
// 32 t x 16 channel-groups (8 ch each). qp replicated per block (cheap).
__device__ __forceinline__ void attn_energies(
    AttnS* A, const _Float16* __restrict__ keys16, const _Float16* __restrict__ h1,
    const _Float16* __restrict__ qwT, const float* __restrict__ qb,
    const float* __restrict__ vw, const float* __restrict__ vb,
    const float* __restrict__ Mf, const float* __restrict__ Lbf,
    const float* __restrict__ wcumL, float* __restrict__ eG,
    int b, int sub, int tid) {
  if (tid < 256) ((h4*)A->h1l)[tid] = *(const h4*)(h1 + b * 1024 + tid * 4);
  if (tid < 62) {
    int g = sub * 32 - 15 + tid;
    A->wl[tid] = (g >= 0 && g < TIN) ? wcumL[g] : 0.f;
  }
  __syncthreads();
  {  // qp partials
    int a = tid & 127, kq = tid >> 7;
    const _Float16* hr = A->h1l + kq * 256;
    const _Float16* qr = qwT + a * 1024 + kq * 256;
    float s = 0.f;
#pragma unroll 4
    for (int i = 0; i < 32; ++i)
      s = dot8(*(const h8*)(hr + i * 8), *(const h8*)(qr + i * 8), s);
    A->qpart[kq * AA + a] = s;
  }
  __syncthreads();
  if (tid < AA)
    A->qp[tid] = A->qpart[tid] + A->qpart[AA + tid] + A->qpart[2 * AA + tid] +
                 A->qpart[3 * AA + tid] + qb[tid];
  __syncthreads();
  {
    int tl = tid >> 4, cg = tid & 15, c8 = cg * 8;
    int t = sub * 32 + tl;
    h8 kv = *(const h8*)(keys16 + ((size_t)(b * TIN + t)) * AA + c8);
    float l8[8];
    const float4* Lb4 = (const float4*)(Lbf + c8);
    float4 v0 = Lb4[0], v1 = Lb4[1];
    l8[0]=v0.x; l8[1]=v0.y; l8[2]=v0.z; l8[3]=v0.w;
    l8[4]=v1.x; l8[5]=v1.y; l8[6]=v1.z; l8[7]=v1.w;
    for (int kk = 0; kk < KSZ; ++kk) {
      float wk = A->wl[tl + kk];
      const float4* Mr = (const float4*)(Mf + kk * AA + c8);
      float4 m0 = Mr[0], m1 = Mr[1];
      l8[0]=fmaf(wk,m0.x,l8[0]); l8[1]=fmaf(wk,m0.y,l8[1]);
      l8[2]=fmaf(wk,m0.z,l8[2]); l8[3]=fmaf(wk,m0.w,l8[3]);
      l8[4]=fmaf(wk,m1.x,l8[4]); l8[5]=fmaf(wk,m1.y,l8[5]);
      l8[6]=fmaf(wk,m1.z,l8[6]); l8[7]=fmaf(wk,m1.w,l8[7]);
    }
    const float4* vw4 = (const float4*)(vw + c8);
    float4 w0 = vw4[0], w1 = vw4[1];
    float vwa[8] = {w0.x, w0.y, w0.z, w0.w, w1.x, w1.y, w1.z, w1.w};
    float e = 0.f;
#pragma unroll
    for (int j = 0; j < 8; ++j) {
      float u = fast_tanh(A->qp[c8 + j] + (float)kv[j] + l8[j]);
      e = fmaf(u, vwa[j], e);
    }
    e += __shfl_xor(e, 8, 16);
    e += __shfl_xor(e, 4, 16);
    e += __shfl_xor(e, 2, 16);
    e += __shfl_xor(e, 1, 16);
    if (cg == 0) st_cc4f(eG + b * 256 + t, e + vb[0]);
  }
}

// P3: softmax (replicated, deterministic) + wcum + alignments t-slice +
// ctx channel-slice [sub*64, sub*64+64).
__device__ __forceinline__ void attn_softctx(
    AttnS* A, const _Float16* __restrict__ memT, const float* __restrict__ eG,
    float* __restrict__ wcumL, _Float16* __restrict__ ctxo,
    float* __restrict__ out, int b, int sub, int step, int tid) {
  if (tid < 256) {
    float e = ld_cc4f(eG + b * 256 + tid);
    A->red[tid] = e;
    A->epart[tid] = e;
  }
  __syncthreads();
  for (int s = 128; s > 0; s >>= 1) {
    if (tid < s) A->red[tid] = fmaxf(A->red[tid], A->red[tid + s]);
    __syncthreads();
  }
  float mx = A->red[0];
  __syncthreads();
  float pp = 0.f;
  if (tid < 256) { pp = __expf(A->epart[tid] - mx); A->red[tid] = pp; }
  __syncthreads();
  for (int s = 128; s > 0; s >>= 1) {
    if (tid < s) A->red[tid] += A->red[tid + s];
    __syncthreads();
  }
  if (tid < 256) {
    float w = pp / A->red[0];
    A->wsm16[tid] = (_Float16)w;
    wcumL[tid] += w;
    if ((tid >> 5) == sub)
      st_cc4f(out + 1036800 + (size_t)b * TOUT * TIN + step * TIN + tid, w);
  }
  __syncthreads();
  {  // ctx slice: 64 channels x 8 t-groups
    int ch = tid & 63, tg = tid >> 6;
    const _Float16* mr = memT + ((size_t)(b * EE + sub * 64 + ch)) * TIN + tg * 32;
    const _Float16* wp = A->wsm16 + tg * 32;
    float s = 0.f;
#pragma unroll
    for (int i = 0; i < 4; ++i)
      s = dot8(*(const h8*)(wp + i * 8), *(const h8*)(mr + i * 8), s);
    A->qpart[ch * 8 + tg] = s;
  }
  __syncthreads();
  if (tid < 64) {
    const float* p = A->qpart + tid * 8;
    A->ctx16[tid] = (_Float16)(p[0]+p[1]+p[2]+p[3]+p[4]+p[5]+p[6]+p[7]);
  }
  __syncthreads();
  if (tid < 16)
    st_cc8(ctxo + b * 512 + sub * 64 + tid * 4, *(const h4*)(A->ctx16 + tid * 4));
}

// Deferred mel/gate for step `step` (runs in P0 of step+1; inputs from rings).
// sub owns outputs o = sub*10 + j (j<10; sub==7 also j=10 -> o=80=gate).
__device__ __forceinline__ void mel_out(
    const _Float16* __restrict__ h1r, const _Float16* __restrict__ ctr,
    const _Float16* __restrict__ pwpT, const float* __restrict__ pb,
    const float* __restrict__ gb_out, float* __restrict__ out,
    int b, int sub, int step, int tid) {
  int j = tid >> 5, lane = tid & 31;
  int no = (sub == 7) ? 11 : 10;
  if (j < no) {
    int o = sub * 10 + j;
    int k0 = lane * 48;
    const _Float16* pr = pwpT + o * 1536 + k0;
    float s = 0.f;
#pragma unroll
    for (int i = 0; i < 6; ++i) {
      int k = k0 + i * 8;
      h8 xv = (k < DD) ? *(const h8*)(h1r + b * 1024 + k)
                       : *(const h8*)(ctr + b * 512 + (k - DD));
      s = dot8(xv, *(const h8*)(pr + i * 8), s);
    }
    s += __shfl_down(s, 16, 32);
    s += __shfl_down(s, 8, 32);
    s += __shfl_down(s, 4, 32);
    s += __shfl_down(s, 2, 32);
    s += __shfl_down(s, 1, 32);
    if (lane == 0) {
      if (o < 80)
        st_cc4f(out + (size_t)b * TOUT * NMEL + step * NMEL + o, s + pb[o]);
      else
        st_cc4f(out + 1024000 + b * TOUT + step, s + gb_out[0]);
    }
  }
}

__global__ __launch_bounds__(512, 2) void k_decoder(
    const _Float16* __restrict__ memT, const _Float16* __restrict__ px,
    const _Float16* __restrict__ keys16, const _Float16* __restrict__ Wstage,
    const float* __restrict__ l0b, const float* __restrict__ l1b,
    const _Float16* __restrict__ qwT, const float* __restrict__ qb,
    const float* __restrict__ vw, const float* __restrict__ vb,
    const float* __restrict__ Mf, const float* __restrict__ Lbf,
    const _Float16* __restrict__ pwpT, const float* __restrict__ pb,
    const float* __restrict__ gb_out,
    char* state, float* out) {
  extern __shared__ char smem[];
  _Float16* Wl   = (_Float16*)smem;                // 139,520
  char* uni      = smem + 139520;                  // 17,664 union
  float* zsP     = (float*)uni;                    // 17,408 (lstm mfma partials)
  _Float16* hbuf = (_Float16*)(uni + 17408);       // 256   (lstm)
  AttnS* A       = (AttnS*)uni;                    // 12,408 (attn)
  float* cst     = (float*)(smem + 157184);        // 1,024
  float* gb      = (float*)(smem + 158208);        // 128
  float* wcumL   = (float*)(smem + 158336);        // 1,024  -> total 159,360

  // state: 8 x h0(64KB) | 8 x h1(64KB) | 8 x ctx(32KB) | bar(8KB) | eG(32KB)
  _Float16* h0R  = (_Float16*)state;
  _Float16* h1R  = (_Float16*)(state + 524288);
  _Float16* ctxR = (_Float16*)(state + 1048576);
  int* bar       = (int*)(state + 1310720);
  float* eG      = (float*)(state + 1318912);      // [32][256] energies exch

  const int B = blockIdx.x, tid = threadIdx.x;
  const int b = B >> 3, sub = B & 7;               // 8 blocks per batch

  __builtin_amdgcn_fence(__ATOMIC_RELEASE, "agent");

  {  // load this block's weight slice into LDS (read-only, once)
    const float4* src = (const float4*)(Wstage + (size_t)B * 16 * KP);
    float4* dst = (float4*)Wl;
    for (int i = tid; i < 16 * KP * 2 / 16; i += 512) dst[i] = src[i];
  }
  if (tid < 256) { cst[tid] = 0.f; wcumL[tid] = 0.f; }
  if (tid < 32) {
    int c = tid & 15;
    const float* bb = (tid < 16) ? l0b : l1b;
    gb[tid] = bb[(c & 3) * 1024 + B * 4 + (c >> 2)];
  }
  __syncthreads();

  for (int t = 0; t < TOUT; ++t) {
    const int s = t & (NRING - 1), sm1 = (t + NRING - 1) & (NRING - 1);
    _Float16* h0n = h0R + s * 32768;
    _Float16* h0o = h0R + sm1 * 32768;
    _Float16* h1n = h1R + s * 32768;
    _Float16* h1o = h1R + sm1 * 32768;
    _Float16* ctn = ctxR + s * 16384;
    _Float16* cto = ctxR + sm1 * 16384;
    const bool inv = ((t & 3) == 3);

    // P0: LSTM0 + deferred mel[t-1] (independent of LSTM0; no LDS use)
    lstm_phase<256, 512, 1024, 0, 0>(Wl, zsP, hbuf, cst, gb,
                                     px + (size_t)t * 8192, cto, h0o,
                                     px, h0n, B, tid);
    if (t > 0)
      mel_out(h1R + sm1 * 32768, ctxR + sm1 * 16384, pwpT, pb, gb_out, out,
              b, sub, t - 1, tid);
    gbar(bar, 4 * t + 0, tid, false);
    // P1: LSTM1
    lstm_phase<0, 1024, 512, 1024, 1792>(Wl, zsP, hbuf, cst + 128, gb + 16,
                                         px, h0n, cto, h1o,
                                         h1n, B, tid);
    gbar(bar, 4 * t + 1, tid, false);
    // P2: energies (all 256 blocks; 8 per batch)
    attn_energies(A, keys16, h1n, qwT, qb, vw, vb, Mf, Lbf, wcumL, eG,
                  b, sub, tid);
    gbar(bar, 4 * t + 2, tid, false);
    // P3: softmax + ctx slice
    attn_softctx(A, memT, eG, wcumL, ctn, out, b, sub, t, tid);
    gbar(bar, 4 * t + 3, tid, inv);
  }
  {  // final mel for t = TOUT-1 (ctx/h1 rings complete after last barrier)
    const int sl = (TOUT - 1) & (NRING - 1);
    mel_out(h1R + sl * 32768, ctxR + sl * 16384, pwpT, pb, gb_out, out,
            b, sub, TOUT - 1, tid);
  }
}

// ---------------- host ----------------
extern "C" void kernel_launch(void* const* d_in, const int* in_sizes, int n_in,
                              void* d_out, int out_size, void* d_ws, size_t ws_size,
                              hipStream_t stream) {
  const float* memory  = (const float*)d_in[0];
  const float* targets = (const float*)d_in[1];
  const float* p1w = (const float*)d_in[3];
  const float* p1b = (const float*)d_in[4];
  const float* p2w = (const float*)d_in[5];
  const float* p2b = (const float*)d_in[6];
  const float* l0k = (const float*)d_in[7];
  const float* l0r = (const float*)d_in[8];
  const float* l0b = (const float*)d_in[9];
  const float* l1k = (const float*)d_in[10];
  const float* l1r = (const float*)d_in[11];
  const float* l1b = (const float*)d_in[12];
  const float* qw  = (const float*)d_in[13];
  const float* qb  = (const float*)d_in[14];
  const float* mw  = (const float*)d_in[15];
  const float* mb  = (const float*)d_in[16];
  const float* vw  = (const float*)d_in[17];
  const float* vb  = (const float*)d_in[18];
  const float* cw  = (const float*)d_in[19];
  const float* cb  = (const float*)d_in[20];
  const float* ldw = (const float*)d_in[21];
  const float* ldb = (const float*)d_in[22];
  const float* pw  = (const float*)d_in[23];
  const float* pb  = (const float*)d_in[24];
  const float* gw  = (const float*)d_in[25];
  const float* gb  = (const float*)d_in[26];

  char* W = (char*)d_ws;
  _Float16* px16   = (_Float16*)(W + 0);           //  6,553,600
  _Float16* keys16 = (_Float16*)(W + 6553600);     //  2,097,152
  _Float16* memT16 = (_Float16*)(W + 8650752);     //  8,388,608
  _Float16* qwT16  = (_Float16*)(W + 17039360);    //    262,144
  _Float16* pwpT   = (_Float16*)(W + 17301504);    //    393,216
  float*    Mf     = (float*)   (W + 17694720);    //     15,872
  float*    Lbf    = (float*)   (W + 17710592);    //        512
  _Float16* Wstage = (_Float16*)(W + 17711104);    // 35,717,120
  char*     state  =             W + 53428224;     //  1,351,680 (rings+bar+eG)
  float* out = (float*)d_out;

  // zero state rings + barrier flags + eG (ws re-poisoned before every call)
  hipMemsetAsync(state, 0, 1351680, stream);

  k_prenet<<<TOUT * BB, PRE, 0, stream>>>(targets, p1w, p1b, p2w, p2b, px16);
  k_keys<<<BB * TIN, AA, 0, stream>>>(memory, mw, mb, keys16);
  k_locM<<<1, AA, 0, stream>>>(cw, cb, ldw, ldb, Mf, Lbf);
  k_memT<<<4096, 256, 0, stream>>>(memory, memT16);
  k_castT<<<(131072 + 255) / 256, 256, 0, stream>>>(qw, qwT16);
  k_permP<<<768, 256, 0, stream>>>(pw, gw, pwpT);
  // weight slices: rows [l0k 0..767 | l0r 768..1791 | l1k 1792..3327 | l1r 3328..4351]
  k_perm<<<(768 * 1024 + 255) / 256, 256, 0, stream>>>(l0k, Wstage, 768, 0);
  k_perm<<<(1024 * 1024 + 255) / 256, 256, 0, stream>>>(l0r, Wstage, 1024, 768);
  k_perm<<<(1536 * 1024 + 255) / 256, 256, 0, stream>>>(l1k, Wstage, 1536, 1792);
  k_perm<<<(1024 * 1024 + 255) / 256, 256, 0, stream>>>(l1r, Wstage, 1024, 1792 + 1536);

  void* args[] = {(void*)&memT16, (void*)&px16, (void*)&keys16, (void*)&Wstage,
                  (void*)&l0b, (void*)&l1b, (void*)&qwT16, (void*)&qb,
                  (void*)&vw, (void*)&vb, (void*)&Mf, (void*)&Lbf,
                  (void*)&pwpT, (void*)&pb, (void*)&gb,
                  (void*)&state, (void*)&out};
  hipLaunchCooperativeKernel((const void*)k_decoder, dim3(256), dim3(512), args,
                             159360, stream);
}